// Round 1
// baseline (5351.205 us; speedup 1.0000x reference)
//
#include <hip/hip_runtime.h>
#include <hip/hip_bf16.h>
#include <math.h>

// ---------------------------------------------------------------------------
// Sizes
//   x: (256,1,22,1000)  conv1 (22,1,22,1) VALID -> (256,22,1,1000)
//   conv2 (25,22,1,12) pad (6,6) -> (256,25,1,1001); sig=(256,25,1001)
//   epochs lens = [334,334,333], offsets 0,334,668
//   covs: (256,3,25,25); windows m=30 (k=2:16, k=3:9, k=4:4, k=5:1)
// ---------------------------------------------------------------------------

// ---------------- conv1 + bn1 ----------------
__global__ __launch_bounds__(256) void conv1_kernel(
    const float* __restrict__ x, const float* __restrict__ c1w, const float* __restrict__ c1b,
    const float* __restrict__ g, const float* __restrict__ be, const float* __restrict__ mu,
    const float* __restrict__ va, float* __restrict__ ybn1)
{
  __shared__ float w[484];
  __shared__ float scl[22], sft[22];
  int t = threadIdx.x;
  for (int e = t; e < 484; e += 256) w[e] = c1w[e];           // c1w[o][0][h][0] -> o*22+h
  if (t < 22) { float inv = g[t] / sqrtf(va[t] + 1e-5f); scl[t] = inv; sft[t] = be[t] - mu[t]*inv; }
  __syncthreads();
  int gid = blockIdx.x*256 + t;                               // 256*1000 exactly
  int b = gid / 1000, wp = gid % 1000;
  const float* xb = x + (size_t)b*22000 + wp;
  float acc[22];
  #pragma unroll
  for (int o = 0; o < 22; ++o) acc[o] = c1b[o];
  for (int h = 0; h < 22; ++h) {
    float xv = xb[h*1000];
    #pragma unroll
    for (int o = 0; o < 22; ++o) acc[o] += xv * w[o*22 + h];
  }
  float* yb = ybn1 + (size_t)b*22000 + wp;
  #pragma unroll
  for (int o = 0; o < 22; ++o) yb[o*1000] = acc[o]*scl[o] + sft[o];
}

// ---------------- conv2 + bn2 ----------------
__global__ __launch_bounds__(256) void conv2_kernel(
    const float* __restrict__ ybn1, const float* __restrict__ c2w, const float* __restrict__ c2b,
    const float* __restrict__ g, const float* __restrict__ be, const float* __restrict__ mu,
    const float* __restrict__ va, float* __restrict__ sig)
{
  __shared__ float w[6600];                                   // c2w[p][c][0][kw] -> p*264 + c*12 + kw
  __shared__ float scl[25], sft[25];
  int t = threadIdx.x;
  for (int e = t; e < 6600; e += 256) w[e] = c2w[e];
  if (t < 25) { float inv = g[t] / sqrtf(va[t] + 1e-5f); scl[t] = inv; sft[t] = be[t] - mu[t]*inv; }
  __syncthreads();
  int gid = blockIdx.x*256 + t;
  if (gid >= 256*1001) return;
  int b = gid / 1001, wp = gid % 1001;
  const float* yb = ybn1 + (size_t)b*22000;
  float acc[25];
  #pragma unroll
  for (int p = 0; p < 25; ++p) acc[p] = c2b[p];
  for (int c = 0; c < 22; ++c) {
    for (int kw = 0; kw < 12; ++kw) {
      int wi = wp - 6 + kw;
      if (wi < 0 || wi >= 1000) continue;
      float v = yb[c*1000 + wi];
      #pragma unroll
      for (int p = 0; p < 25; ++p) acc[p] += v * w[p*264 + c*12 + kw];
    }
  }
  float* sb = sig + (size_t)b*25025 + wp;
  #pragma unroll
  for (int p = 0; p < 25; ++p) sb[p*1001] = acc[p]*scl[p] + sft[p];
}

// ---------------- signal2spd: per (b,epoch) covariance ----------------
__global__ __launch_bounds__(256) void spd_kernel(const float* __restrict__ sig, float* __restrict__ covs)
{
  __shared__ float s[25*334];
  __shared__ float mean[25];
  __shared__ float cv[625];
  __shared__ float tra;
  int bt = blockIdx.x; int b = bt/3, ep = bt%3;
  int off = ep*334;
  int Lp = (ep < 2) ? 334 : 333;
  int t = threadIdx.x;
  const float* sb = sig + (size_t)b*25025;
  for (int e = t; e < 25*Lp; e += 256) { int c = e / Lp, tt = e % Lp; s[c*334 + tt] = sb[c*1001 + off + tt]; }
  __syncthreads();
  if (t < 25) { float m = 0.f; for (int i = 0; i < Lp; ++i) m += s[t*334 + i]; mean[t] = m / (float)Lp; }
  __syncthreads();
  for (int pi = t; pi < 325; pi += 256) {
    int i = 0, rem = pi;
    while (rem >= 25 - i) { rem -= 25 - i; ++i; }
    int j = i + rem;
    float mi = mean[i], mj = mean[j], acc = 0.f;
    for (int k = 0; k < Lp; ++k) acc += (s[i*334 + k] - mi) * (s[j*334 + k] - mj);
    float v = acc / (float)(Lp - 1);
    cv[i*25 + j] = v; cv[j*25 + i] = v;
  }
  __syncthreads();
  if (t == 0) { float tr = 0.f; for (int i = 0; i < 25; ++i) tr += cv[i*26]; tra = tr; }
  __syncthreads();
  float inv = 1.f / tra;
  for (int e = t; e < 625; e += 256) {
    int i = e / 25, j = e % 25;
    covs[(size_t)bt*625 + e] = cv[e]*inv + ((i == j) ? 1e-5f : 0.f);
  }
}

// ---------------- build V (25x25, jitter), K (4x4, jitter), Q29 (4x4, jitter) ----------------
__global__ __launch_bounds__(64) void build_windows_kernel(
    const float* __restrict__ covs,
    const float* __restrict__ sk0, const float* __restrict__ sk1, const float* __restrict__ sk2, const float* __restrict__ sk3,
    const float* __restrict__ sv0, const float* __restrict__ sv1, const float* __restrict__ sv2, const float* __restrict__ sv3,
    const float* __restrict__ sq3,
    float* __restrict__ Vbuf, float* __restrict__ Kbuf, float* __restrict__ Qbuf)
{
  __shared__ float sSub[625], sSv[625], sTmp[625], sSk[100], sTk[100];
  int bw = blockIdx.x;            // bt*30 + win
  int bt = bw / 30, win = bw % 30;
  int t = threadIdx.x;
  int k, r0, c0;
  const float* sv; const float* sk;
  if (win < 16)      { k = 2; r0 = win/4;        c0 = win%4;        sv = sv0; sk = sk0; }
  else if (win < 25) { k = 3; int u = win-16; r0 = u/3; c0 = u%3;   sv = sv1; sk = sk1; }
  else if (win < 29) { k = 4; int u = win-25; r0 = u/2; c0 = u%2;   sv = sv2; sk = sk2; }
  else               { k = 5; r0 = 0;            c0 = 0;            sv = sv3; sk = sk3; }
  int kk = k*k;
  const float* cov = covs + (size_t)bt*625;
  for (int e = t; e < kk*kk; e += 64) {
    int p = e / kk, q = e % kk;
    int ip = (r0 + p/k)*5 + (c0 + p%k);
    int iq = (r0 + q/k)*5 + (c0 + q%k);
    sSub[p*kk + q] = cov[ip*25 + iq];
  }
  for (int e = t; e < kk*25; e += 64) sSv[e] = sv[e];
  for (int e = t; e < kk*4; e += 64)  sSk[e] = sk[e];
  __syncthreads();
  for (int e = t; e < kk*25; e += 64) {                       // tmp = sub @ sv  (kk x 25)
    int i = e / 25, b = e % 25;
    float acc = 0.f;
    for (int j = 0; j < kk; ++j) acc += sSub[i*kk + j] * sSv[j*25 + b];
    sTmp[e] = acc;
  }
  for (int e = t; e < kk*4; e += 64) {                        // tmpK = sub @ sk (kk x 4)
    int i = e / 4, b = e % 4;
    float acc = 0.f;
    for (int j = 0; j < kk; ++j) acc += sSub[i*kk + j] * sSk[j*4 + b];
    sTk[e] = acc;
  }
  __syncthreads();
  float* Vout = Vbuf + (size_t)bw*625;
  for (int e = t; e < 625; e += 64) {                         // V = sv^T tmp + jitter(25)
    int a = e / 25, b = e % 25;
    float acc = 0.f;
    for (int i = 0; i < kk; ++i) acc += sSv[i*25 + a] * sTmp[i*25 + b];
    if (a == b) acc += 4e-6f * (float)(1 + a);
    Vout[e] = acc;
  }
  float* Kout = Kbuf + (size_t)bw*16;
  for (int e = t; e < 16; e += 64) {                          // K = sk^T tmpK + jitter(4)
    int a = e / 4, b = e % 4;
    float acc = 0.f;
    for (int i = 0; i < kk; ++i) acc += sSk[i*4 + a] * sTk[i*4 + b];
    if (a == b) acc += 2.5e-5f * (float)(1 + a);
    Kout[e] = acc;
  }
  if (win == 29) {                                            // Q29 = sq3^T cov sq3 + jitter(4)
    __syncthreads();
    for (int e = t; e < 100; e += 64) {
      int i = e / 4, b = e % 4;
      float acc = 0.f;
      for (int j = 0; j < 25; ++j) acc += sSub[i*25 + j] * sq3[j*4 + b];
      sTk[e] = acc;
    }
    __syncthreads();
    float* Qout = Qbuf + (size_t)bt*16;
    for (int e = t; e < 16; e += 64) {
      int a = e / 4, b = e % 4;
      float acc = 0.f;
      for (int i = 0; i < 25; ++i) acc += sq3[i*4 + a] * sTk[i*4 + b];
      if (a == b) acc += 2.5e-5f * (float)(1 + a);
      Qout[e] = acc;
    }
  }
}

// ---------------- batched eigh (wave-parallel tournament Jacobi) ----------------
// MODE 0: f=log(max(w,1e-9));  MODE 1: f=max(exp(w),1e-4);  MODE 2: f=max(w, ln 1e-4)
template<int NPAD, int NDATA, int MODE, int NSWEEPS>
__global__ __launch_bounds__(64) void eigh_kernel(float* __restrict__ mats, float* __restrict__ norms)
{
  constexpr int NP = NPAD/2;
  constexpr int NR = NPAD-1;
  constexpr int LD = NPAD + 1;
  __shared__ float A[NPAD*LD];
  __shared__ float U[NPAD*LD];
  __shared__ float cs_c[NP], cs_s[NP];
  __shared__ int   pr_p[NP], pr_q[NP];
  __shared__ float fv[NPAD];
  int t = threadIdx.x;
  float* M = mats + (size_t)blockIdx.x * (NDATA*NDATA);
  for (int e = t; e < NPAD*NPAD; e += 64) {
    int i = e / NPAD, j = e % NPAD;
    float v = 0.f;
    if (i < NDATA && j < NDATA) v = 0.5f*(M[i*NDATA + j] + M[j*NDATA + i]);
    A[i*LD + j] = v;
    U[i*LD + j] = (i == j) ? 1.f : 0.f;
  }
  __syncthreads();
  for (int sw = 0; sw < NSWEEPS; ++sw) {
    for (int r = 0; r < NR; ++r) {
      if (t < NP) {
        int p, q;
        if (t == 0) { p = NPAD-1; q = r; }
        else { p = (r + t) % NR; q = (r - t + NR) % NR; }
        float app = A[p*LD + p], aqq = A[q*LD + q], apq = A[p*LD + q];
        float c = 1.f, s = 0.f;
        if (fabsf(apq) > 1e-36f) {
          float tau = (aqq - app) / (2.f*apq);
          float tt = 1.f / (fabsf(tau) + sqrtf(tau*tau + 1.f));
          tt = (tau >= 0.f) ? tt : -tt;
          c = rsqrtf(tt*tt + 1.f);
          s = tt * c;
        }
        cs_c[t] = c; cs_s[t] = s; pr_p[t] = p; pr_q[t] = q;
      }
      __syncthreads();
      for (int e = t; e < NP*NPAD; e += 64) {                 // A <- A * J  (columns p,q)
        int i = e / NPAD, kx = e % NPAD;
        int p = pr_p[i], q = pr_q[i];
        float c = cs_c[i], s = cs_s[i];
        float akp = A[kx*LD + p], akq = A[kx*LD + q];
        A[kx*LD + p] = c*akp - s*akq;
        A[kx*LD + q] = s*akp + c*akq;
      }
      __syncthreads();
      for (int e = t; e < NP*NPAD; e += 64) {                 // A <- J^T * A ; U <- U * J
        int i = e / NPAD, kx = e % NPAD;
        int p = pr_p[i], q = pr_q[i];
        float c = cs_c[i], s = cs_s[i];
        float apk = A[p*LD + kx], aqk = A[q*LD + kx];
        A[p*LD + kx] = c*apk - s*aqk;
        A[q*LD + kx] = s*apk + c*aqk;
        float ukp = U[kx*LD + p], ukq = U[kx*LD + q];
        U[kx*LD + p] = c*ukp - s*ukq;
        U[kx*LD + q] = s*ukp + c*ukq;
      }
      __syncthreads();
    }
  }
  if (t < NPAD) {
    float wv = A[t*LD + t];
    float f;
    if (MODE == 0)      f = logf(fmaxf(wv, 1e-9f));
    else if (MODE == 1) f = fmaxf(expf(wv), 1e-4f);
    else                f = fmaxf(wv, -9.210340371976182f);
    fv[t] = (t < NDATA) ? f : 0.f;
  }
  __syncthreads();
  float nacc = 0.f;
  for (int e = t; e < NDATA*NDATA; e += 64) {                 // M = U f(W) U^T (in place)
    int i = e / NDATA, j = e % NDATA;
    float acc = 0.f;
    for (int kx = 0; kx < NPAD; ++kx) acc += U[i*LD + kx] * fv[kx] * U[j*LD + kx];
    M[e] = acc;
    nacc += acc*acc;
  }
  if (norms != nullptr) {
    #pragma unroll
    for (int off = 32; off > 0; off >>= 1) nacc += __shfl_down(nacc, off);
    if (t == 0) norms[blockIdx.x] = nacc;
  }
}

// ---------------- per-thread 4x4 eigh -> log, plus Frobenius^2 norm ----------------
template<int P, int Q>
__device__ __forceinline__ void rot4(float a[4][4], float u[4][4])
{
  float apq = a[P][Q];
  if (fabsf(apq) < 1e-36f) return;
  float app = a[P][P], aqq = a[Q][Q];
  float tau = (aqq - app) / (2.f*apq);
  float tt = 1.f / (fabsf(tau) + sqrtf(tau*tau + 1.f));
  if (tau < 0.f) tt = -tt;
  float c = 1.f / sqrtf(tt*tt + 1.f), s = tt*c;
  #pragma unroll
  for (int k = 0; k < 4; ++k) { float akp = a[k][P], akq = a[k][Q]; a[k][P] = c*akp - s*akq; a[k][Q] = s*akp + c*akq; }
  #pragma unroll
  for (int k = 0; k < 4; ++k) { float apk = a[P][k], aqk = a[Q][k]; a[P][k] = c*apk - s*aqk; a[Q][k] = s*apk + c*aqk; }
  #pragma unroll
  for (int k = 0; k < 4; ++k) { float ukp = u[k][P], ukq = u[k][Q]; u[k][P] = c*ukp - s*ukq; u[k][Q] = s*ukp + c*ukq; }
}

__global__ __launch_bounds__(256) void eigh4_kernel(float* __restrict__ kmats, float* __restrict__ qmats,
                                                    float* __restrict__ norms)
{
  int idx = blockIdx.x*256 + threadIdx.x;
  if (idx >= 23808) return;
  float* M = (idx < 23040) ? (kmats + (size_t)idx*16) : (qmats + (size_t)(idx - 23040)*16);
  float a[4][4], u[4][4];
  #pragma unroll
  for (int i = 0; i < 4; ++i)
    #pragma unroll
    for (int j = 0; j < 4; ++j) { a[i][j] = 0.5f*(M[i*4+j] + M[j*4+i]); u[i][j] = (i == j) ? 1.f : 0.f; }
  #pragma unroll 1
  for (int sw = 0; sw < 8; ++sw) {
    rot4<0,1>(a,u); rot4<0,2>(a,u); rot4<0,3>(a,u);
    rot4<1,2>(a,u); rot4<1,3>(a,u); rot4<2,3>(a,u);
  }
  float f[4];
  #pragma unroll
  for (int i = 0; i < 4; ++i) f[i] = logf(fmaxf(a[i][i], 1e-9f));
  float nrm = 0.f;
  #pragma unroll
  for (int i = 0; i < 4; ++i)
    #pragma unroll
    for (int j = 0; j < 4; ++j) {
      float acc = 0.f;
      #pragma unroll
      for (int k = 0; k < 4; ++k) acc += u[i][k]*f[k]*u[j][k];
      M[i*4+j] = acc; nrm += acc*acc;
    }
  norms[idx] = nrm;
}

// ---------------- attention 1: only output row j=29 needed ----------------
__global__ __launch_bounds__(64) void att1_kernel(
    const float* __restrict__ logK, const float* __restrict__ logQ,
    const float* __restrict__ kn, const float* __restrict__ qn,
    const float* __restrict__ logV, float* __restrict__ outlog1)
{
  __shared__ float lq[16];
  __shared__ float sscore[30];
  __shared__ float sp[30];
  int bt = blockIdx.x, t = threadIdx.x;
  if (t < 16) lq[t] = logQ[(size_t)bt*16 + t];
  __syncthreads();
  if (t < 30) {
    const float* lk = logK + ((size_t)bt*30 + t)*16;
    float cr = 0.f;
    #pragma unroll
    for (int e = 0; e < 16; ++e) cr += lk[e]*lq[e];
    float E = fmaxf(kn[bt*30 + t] + qn[bt] - 2.f*cr, 0.f);
    sscore[t] = 1.f/(1.f + log1pf(E));
  }
  __syncthreads();
  float mx = -1e30f;
  for (int i = 0; i < 30; ++i) mx = fmaxf(mx, sscore[i]);
  float sm = 0.f;
  for (int i = 0; i < 30; ++i) sm += expf(sscore[i] - mx);
  if (t < 30) sp[t] = expf(sscore[t] - mx)/sm;
  __syncthreads();
  const float* lv = logV + (size_t)bt*30*625;
  float* outp = outlog1 + (size_t)bt*625;
  for (int e = t; e < 625; e += 64) {
    float acc = 0.f;
    for (int i = 0; i < 30; ++i) acc += sp[i]*lv[(size_t)i*625 + e];
    outp[e] = acc;                      // symmetrization folded into next eigh's load
  }
}

// ---------------- stage D: Q2/K2/V2 = W^T xm W (18x18) ----------------
__global__ __launch_bounds__(64) void qkv2_kernel(
    const float* __restrict__ xm, const float* __restrict__ mq, const float* __restrict__ mk,
    const float* __restrict__ mv, float* __restrict__ q2, float* __restrict__ k2, float* __restrict__ v2)
{
  __shared__ float sx[625], sw[450], stmp[450];
  int bt = blockIdx.x, t = threadIdx.x;
  for (int e = t; e < 625; e += 64) sx[e] = xm[(size_t)bt*625 + e];
  for (int wi = 0; wi < 3; ++wi) {
    const float* W = (wi == 0) ? mq : (wi == 1) ? mk : mv;
    float* O = ((wi == 0) ? q2 : (wi == 1) ? k2 : v2) + (size_t)bt*324;
    for (int e = t; e < 450; e += 64) sw[e] = W[e];
    __syncthreads();
    for (int e = t; e < 450; e += 64) {
      int i = e / 18, b = e % 18;
      float acc = 0.f;
      for (int j = 0; j < 25; ++j) acc += sx[i*25 + j]*sw[j*18 + b];
      stmp[e] = acc;
    }
    __syncthreads();
    for (int e = t; e < 324; e += 64) {
      int a = e / 18, b = e % 18;
      float acc = 0.f;
      for (int i = 0; i < 25; ++i) acc += sw[i*18 + a]*stmp[i*18 + b];
      O[e] = acc;
    }
    __syncthreads();
  }
}

// ---------------- attention 2 (m=3, all outputs) ----------------
__global__ __launch_bounds__(64) void att2_kernel(
    const float* __restrict__ logQ2, const float* __restrict__ logK2, const float* __restrict__ logV2,
    const float* __restrict__ norms, float* __restrict__ outlog2)
{
  __shared__ float S[3][3];   // score[i][j]
  __shared__ float PT[3][3];  // P[j][i]
  int b = blockIdx.x, t = threadIdx.x;
  if (t < 9) {
    int i = t / 3, j = t % 3;
    const float* lk = logK2 + ((size_t)b*3 + i)*324;
    const float* lq = logQ2 + ((size_t)b*3 + j)*324;
    float cr = 0.f;
    for (int e = 0; e < 324; ++e) cr += lk[e]*lq[e];
    float E = fmaxf(norms[768 + b*3 + i] + norms[b*3 + j] - 2.f*cr, 0.f);
    S[i][j] = 1.f/(1.f + log1pf(E));
  }
  __syncthreads();
  if (t < 3) {
    float m = fmaxf(S[0][t], fmaxf(S[1][t], S[2][t]));
    float e0 = expf(S[0][t]-m), e1 = expf(S[1][t]-m), e2 = expf(S[2][t]-m);
    float ssum = e0 + e1 + e2;
    PT[t][0] = e0/ssum; PT[t][1] = e1/ssum; PT[t][2] = e2/ssum;
  }
  __syncthreads();
  for (int e = t; e < 324; e += 64) {
    float l0 = logV2[((size_t)b*3 + 0)*324 + e];
    float l1 = logV2[((size_t)b*3 + 1)*324 + e];
    float l2 = logV2[((size_t)b*3 + 2)*324 + e];
    #pragma unroll
    for (int j = 0; j < 3; ++j)
      outlog2[((size_t)b*3 + j)*324 + e] = PT[j][0]*l0 + PT[j][1]*l1 + PT[j][2]*l2;
  }
}

// ---------------- features + final linear ----------------
__global__ __launch_bounds__(64) void feat_kernel(
    const float* __restrict__ Lg, const float* __restrict__ lw, const float* __restrict__ lb,
    float* __restrict__ outp)
{
  __shared__ int tri_i[171], tri_j[171];
  int b = blockIdx.x, t = threadIdx.x;
  if (t == 0) { int f = 0; for (int i = 0; i < 18; ++i) for (int j = i; j < 18; ++j) { tri_i[f] = i; tri_j[f] = j; ++f; } }
  __syncthreads();
  float a0 = 0.f, a1 = 0.f, a2 = 0.f, a3 = 0.f;
  const float SQ2 = 1.41421356237309515f;
  for (int f = t; f < 513; f += 64) {
    int tt = f / 171, r = f % 171;
    int i = tri_i[r], j = tri_j[r];
    float coef = (i == j) ? 1.f : SQ2;
    float v = Lg[((size_t)b*3 + tt)*324 + i*18 + j] * coef;
    a0 += v*lw[0*513 + f]; a1 += v*lw[1*513 + f]; a2 += v*lw[2*513 + f]; a3 += v*lw[3*513 + f];
  }
  #pragma unroll
  for (int off = 32; off > 0; off >>= 1) {
    a0 += __shfl_down(a0, off); a1 += __shfl_down(a1, off);
    a2 += __shfl_down(a2, off); a3 += __shfl_down(a3, off);
  }
  if (t == 0) {
    outp[b*4 + 0] = a0 + lb[0]; outp[b*4 + 1] = a1 + lb[1];
    outp[b*4 + 2] = a2 + lb[2]; outp[b*4 + 3] = a3 + lb[3];
  }
}

// ---------------------------------------------------------------------------
extern "C" void kernel_launch(void* const* d_in, const int* in_sizes, int n_in,
                              void* d_out, int out_size, void* d_ws, size_t ws_size,
                              hipStream_t stream)
{
  const float* x    = (const float*)d_in[0];
  const float* c1w  = (const float*)d_in[1];
  const float* c1b  = (const float*)d_in[2];
  const float* bn1g = (const float*)d_in[3];
  const float* bn1b = (const float*)d_in[4];
  const float* bn1m = (const float*)d_in[5];
  const float* bn1v = (const float*)d_in[6];
  const float* c2w  = (const float*)d_in[7];
  const float* c2b  = (const float*)d_in[8];
  const float* bn2g = (const float*)d_in[9];
  const float* bn2b = (const float*)d_in[10];
  const float* bn2m = (const float*)d_in[11];
  const float* bn2v = (const float*)d_in[12];
  const float* sk0  = (const float*)d_in[14];
  const float* sv0  = (const float*)d_in[15];
  const float* sk1  = (const float*)d_in[17];
  const float* sv1  = (const float*)d_in[18];
  const float* sk2  = (const float*)d_in[20];
  const float* sv2  = (const float*)d_in[21];
  const float* sq3  = (const float*)d_in[22];
  const float* sk3  = (const float*)d_in[23];
  const float* sv3  = (const float*)d_in[24];
  const float* mq   = (const float*)d_in[25];
  const float* mk   = (const float*)d_in[26];
  const float* mv   = (const float*)d_in[27];
  const float* lw   = (const float*)d_in[28];
  const float* lb   = (const float*)d_in[29];
  float* outp = (float*)d_out;

  float* ws = (float*)d_ws;
  // workspace layout (floats); Vbuf reuses dead ybn1+sig space
  float* covs = ws;                       // 768*625        = 480000
  float* ybn1 = ws + 480000;              // 256*22*1000    = 5632000
  float* sig  = ws + 6112000;             // 256*25*1001    = 6406400 -> ends 12518400
  float* Vbuf = ws + 480000;              // 23040*625      = 14400000 -> ends 14880000 (after covs; ybn1/sig dead)
  float* Kbuf = ws + 14880000;            // 23040*16       = 368640
  float* Qbuf = ws + 15248640;            // 768*16         = 12288
  float* knb  = ws + 15260928;            // 23808
  float* ol1  = ws + 15284736;            // 768*625        = 480000   (becomes xm in place)
  float* qkv2 = ws + 15764736;            // 3*768*324      = 746496
  float* nrm2 = ws + 16511232;            // 2304
  float* ol2  = ws + 16513536;            // 768*324        = 248832   (becomes Lg in place)
  // total 16762368 floats = ~64 MiB

  conv1_kernel<<<1000, 256, 0, stream>>>(x, c1w, c1b, bn1g, bn1b, bn1m, bn1v, ybn1);
  conv2_kernel<<<1001, 256, 0, stream>>>(ybn1, c2w, c2b, bn2g, bn2b, bn2m, bn2v, sig);
  spd_kernel<<<768, 256, 0, stream>>>(sig, covs);
  build_windows_kernel<<<23040, 64, 0, stream>>>(covs, sk0, sk1, sk2, sk3, sv0, sv1, sv2, sv3, sq3,
                                                 Vbuf, Kbuf, Qbuf);
  eigh_kernel<26,25,0,10><<<23040, 64, 0, stream>>>(Vbuf, nullptr);        // logV in place
  eigh4_kernel<<<93, 256, 0, stream>>>(Kbuf, Qbuf, knb);                   // logK/logQ + norms
  att1_kernel<<<768, 64, 0, stream>>>(Kbuf, Qbuf, knb, knb + 23040, Vbuf, ol1);
  eigh_kernel<26,25,1,10><<<768, 64, 0, stream>>>(ol1, nullptr);           // xm = rect(exp(.)) in place
  qkv2_kernel<<<768, 64, 0, stream>>>(ol1, mq, mk, mv, qkv2, qkv2 + 248832, qkv2 + 497664);
  eigh_kernel<18,18,0,10><<<2304, 64, 0, stream>>>(qkv2, nrm2);            // logQ2/logK2/logV2 + norms
  att2_kernel<<<256, 64, 0, stream>>>(qkv2, qkv2 + 248832, qkv2 + 497664, nrm2, ol2);
  eigh_kernel<18,18,2,10><<<768, 64, 0, stream>>>(ol2, nullptr);           // Lg = max(w, ln 1e-4) in place
  feat_kernel<<<256, 64, 0, stream>>>(ol2, lw, lb, outp);
}

// Round 3
// 3289.537 us; speedup vs baseline: 1.6267x; 1.6267x over previous
//
#include <hip/hip_runtime.h>
#include <hip/hip_bf16.h>
#include <math.h>

// ---------------------------------------------------------------------------
// Sizes
//   x: (256,1,22,1000)  conv1 (22,1,22,1) VALID -> (256,22,1,1000)
//   conv2 (25,22,1,12) pad (6,6) -> (256,25,1,1001); sig=(256,25,1001)
//   epochs lens = [334,334,333], offsets 0,334,668
//   covs: (256,3,25,25); windows m=30 (k=2:16, k=3:9, k=4:4, k=5:1)
// ---------------------------------------------------------------------------

// ---------------- conv1 + bn1 ----------------
__global__ __launch_bounds__(256) void conv1_kernel(
    const float* __restrict__ x, const float* __restrict__ c1w, const float* __restrict__ c1b,
    const float* __restrict__ g, const float* __restrict__ be, const float* __restrict__ mu,
    const float* __restrict__ va, float* __restrict__ ybn1)
{
  __shared__ float w[484];
  __shared__ float scl[22], sft[22];
  int t = threadIdx.x;
  for (int e = t; e < 484; e += 256) w[e] = c1w[e];           // c1w[o][0][h][0] -> o*22+h
  if (t < 22) { float inv = g[t] / sqrtf(va[t] + 1e-5f); scl[t] = inv; sft[t] = be[t] - mu[t]*inv; }
  __syncthreads();
  int gid = blockIdx.x*256 + t;                               // 256*1000 exactly
  int b = gid / 1000, wp = gid % 1000;
  const float* xb = x + (size_t)b*22000 + wp;
  float acc[22];
  #pragma unroll
  for (int o = 0; o < 22; ++o) acc[o] = c1b[o];
  for (int h = 0; h < 22; ++h) {
    float xv = xb[h*1000];
    #pragma unroll
    for (int o = 0; o < 22; ++o) acc[o] += xv * w[o*22 + h];
  }
  float* yb = ybn1 + (size_t)b*22000 + wp;
  #pragma unroll
  for (int o = 0; o < 22; ++o) yb[o*1000] = acc[o]*scl[o] + sft[o];
}

// ---------------- conv2 + bn2 ----------------
__global__ __launch_bounds__(256) void conv2_kernel(
    const float* __restrict__ ybn1, const float* __restrict__ c2w, const float* __restrict__ c2b,
    const float* __restrict__ g, const float* __restrict__ be, const float* __restrict__ mu,
    const float* __restrict__ va, float* __restrict__ sig)
{
  __shared__ float w[6600];                                   // c2w[p][c][0][kw] -> p*264 + c*12 + kw
  __shared__ float scl[25], sft[25];
  int t = threadIdx.x;
  for (int e = t; e < 6600; e += 256) w[e] = c2w[e];
  if (t < 25) { float inv = g[t] / sqrtf(va[t] + 1e-5f); scl[t] = inv; sft[t] = be[t] - mu[t]*inv; }
  __syncthreads();
  int gid = blockIdx.x*256 + t;
  if (gid >= 256*1001) return;
  int b = gid / 1001, wp = gid % 1001;
  const float* yb = ybn1 + (size_t)b*22000;
  float acc[25];
  #pragma unroll
  for (int p = 0; p < 25; ++p) acc[p] = c2b[p];
  for (int c = 0; c < 22; ++c) {
    for (int kw = 0; kw < 12; ++kw) {
      int wi = wp - 6 + kw;
      if (wi < 0 || wi >= 1000) continue;
      float v = yb[c*1000 + wi];
      #pragma unroll
      for (int p = 0; p < 25; ++p) acc[p] += v * w[p*264 + c*12 + kw];
    }
  }
  float* sb = sig + (size_t)b*25025 + wp;
  #pragma unroll
  for (int p = 0; p < 25; ++p) sb[p*1001] = acc[p]*scl[p] + sft[p];
}

// ---------------- signal2spd: per (b,epoch) covariance ----------------
__global__ __launch_bounds__(256) void spd_kernel(const float* __restrict__ sig, float* __restrict__ covs)
{
  __shared__ float s[25*334];
  __shared__ float mean[25];
  __shared__ float cv[625];
  __shared__ float tra;
  int bt = blockIdx.x; int b = bt/3, ep = bt%3;
  int off = ep*334;
  int Lp = (ep < 2) ? 334 : 333;
  int t = threadIdx.x;
  const float* sb = sig + (size_t)b*25025;
  for (int e = t; e < 25*Lp; e += 256) { int c = e / Lp, tt = e % Lp; s[c*334 + tt] = sb[c*1001 + off + tt]; }
  __syncthreads();
  if (t < 25) { float m = 0.f; for (int i = 0; i < Lp; ++i) m += s[t*334 + i]; mean[t] = m / (float)Lp; }
  __syncthreads();
  for (int pi = t; pi < 325; pi += 256) {
    int i = 0, rem = pi;
    while (rem >= 25 - i) { rem -= 25 - i; ++i; }
    int j = i + rem;
    float mi = mean[i], mj = mean[j], acc = 0.f;
    for (int k = 0; k < Lp; ++k) acc += (s[i*334 + k] - mi) * (s[j*334 + k] - mj);
    float v = acc / (float)(Lp - 1);
    cv[i*25 + j] = v; cv[j*25 + i] = v;
  }
  __syncthreads();
  if (t == 0) { float tr = 0.f; for (int i = 0; i < 25; ++i) tr += cv[i*26]; tra = tr; }
  __syncthreads();
  float inv = 1.f / tra;
  for (int e = t; e < 625; e += 256) {
    int i = e / 25, j = e % 25;
    covs[(size_t)bt*625 + e] = cv[e]*inv + ((i == j) ? 1e-5f : 0.f);
  }
}

// ---------------- build V (25x25, jitter), K (4x4, jitter), Q29 (4x4, jitter) ----------------
__global__ __launch_bounds__(64) void build_windows_kernel(
    const float* __restrict__ covs,
    const float* __restrict__ sk0, const float* __restrict__ sk1, const float* __restrict__ sk2, const float* __restrict__ sk3,
    const float* __restrict__ sv0, const float* __restrict__ sv1, const float* __restrict__ sv2, const float* __restrict__ sv3,
    const float* __restrict__ sq3,
    float* __restrict__ Vbuf, float* __restrict__ Kbuf, float* __restrict__ Qbuf)
{
  __shared__ float sSub[625], sSv[625], sTmp[625], sSk[100], sTk[100];
  int bw = blockIdx.x;            // bt*30 + win
  int bt = bw / 30, win = bw % 30;
  int t = threadIdx.x;
  int k, r0, c0;
  const float* sv; const float* sk;
  if (win < 16)      { k = 2; r0 = win/4;        c0 = win%4;        sv = sv0; sk = sk0; }
  else if (win < 25) { k = 3; int u = win-16; r0 = u/3; c0 = u%3;   sv = sv1; sk = sk1; }
  else if (win < 29) { k = 4; int u = win-25; r0 = u/2; c0 = u%2;   sv = sv2; sk = sk2; }
  else               { k = 5; r0 = 0;            c0 = 0;            sv = sv3; sk = sk3; }
  int kk = k*k;
  const float* cov = covs + (size_t)bt*625;
  for (int e = t; e < kk*kk; e += 64) {
    int p = e / kk, q = e % kk;
    int ip = (r0 + p/k)*5 + (c0 + p%k);
    int iq = (r0 + q/k)*5 + (c0 + q%k);
    sSub[p*kk + q] = cov[ip*25 + iq];
  }
  for (int e = t; e < kk*25; e += 64) sSv[e] = sv[e];
  for (int e = t; e < kk*4; e += 64)  sSk[e] = sk[e];
  __syncthreads();
  for (int e = t; e < kk*25; e += 64) {                       // tmp = sub @ sv  (kk x 25)
    int i = e / 25, b = e % 25;
    float acc = 0.f;
    for (int j = 0; j < kk; ++j) acc += sSub[i*kk + j] * sSv[j*25 + b];
    sTmp[e] = acc;
  }
  for (int e = t; e < kk*4; e += 64) {                        // tmpK = sub @ sk (kk x 4)
    int i = e / 4, b = e % 4;
    float acc = 0.f;
    for (int j = 0; j < kk; ++j) acc += sSub[i*kk + j] * sSk[j*4 + b];
    sTk[e] = acc;
  }
  __syncthreads();
  float* Vout = Vbuf + (size_t)bw*625;
  for (int e = t; e < 625; e += 64) {                         // V = sv^T tmp + jitter(25)
    int a = e / 25, b = e % 25;
    float acc = 0.f;
    for (int i = 0; i < kk; ++i) acc += sSv[i*25 + a] * sTmp[i*25 + b];
    if (a == b) acc += 4e-6f * (float)(1 + a);
    Vout[e] = acc;
  }
  float* Kout = Kbuf + (size_t)bw*16;
  for (int e = t; e < 16; e += 64) {                          // K = sk^T tmpK + jitter(4)
    int a = e / 4, b = e % 4;
    float acc = 0.f;
    for (int i = 0; i < kk; ++i) acc += sSk[i*4 + a] * sTk[i*4 + b];
    if (a == b) acc += 2.5e-5f * (float)(1 + a);
    Kout[e] = acc;
  }
  if (win == 29) {                                            // Q29 = sq3^T cov sq3 + jitter(4)
    __syncthreads();
    for (int e = t; e < 100; e += 64) {
      int i = e / 4, b = e % 4;
      float acc = 0.f;
      for (int j = 0; j < 25; ++j) acc += sSub[i*25 + j] * sq3[j*4 + b];
      sTk[e] = acc;
    }
    __syncthreads();
    float* Qout = Qbuf + (size_t)bt*16;
    for (int e = t; e < 16; e += 64) {
      int a = e / 4, b = e % 4;
      float acc = 0.f;
      for (int i = 0; i < 25; ++i) acc += sq3[i*4 + a] * sTk[i*4 + b];
      if (a == b) acc += 2.5e-5f * (float)(1 + a);
      Qout[e] = acc;
    }
  }
}

// ---------------- batched eigh (wave-parallel tournament Jacobi, v2) ----------------
// MODE 0: f=log(max(w,1e-9));  MODE 1: f=max(exp(w),1e-4);  MODE 2: f=max(w, ln 1e-4)
// One wave per matrix. Hoisted per-thread item coords; packed rotation params
// (int4 byte-offsets + float2 c,s); per-sweep convergence early-exit;
// symmetric (triangle-only) reconstruct with prescaled U.
#define ALDS(off) (*(float*)((char*)A + (off)))
#define ULDS(off) (*(float*)((char*)U + (off)))
#define PQ4(off)  (*(int4*)((char*)pq4 + (off)))
#define CS2(off)  (*(float2*)((char*)cs2 + (off)))

template<int NPAD, int NDATA, int MODE>
__global__ __launch_bounds__(64) void eigh_kernel(float* __restrict__ mats, float* __restrict__ norms)
{
  constexpr int NP = NPAD/2;
  constexpr int NR = NPAD-1;
  constexpr int LD = NPAD + 1;                 // odd -> good bank spread for column access
  constexpr int NITEM = NP*NPAD;               // rotation work items per round
  constexpr int NIT = (NITEM + 63)/64;
  constexpr int LASTV = NITEM - 64*(NIT-1);    // valid lanes in last chunk
  constexpr int NFLAT = NPAD*LD;
  constexpr int NT = NDATA*(NDATA+1)/2;

  __shared__ float A[NPAD*LD];
  __shared__ float U[NPAD*LD];
  __shared__ int4  pq4[NP];                    // {p*4, q*4, p*LD*4, q*LD*4}
  __shared__ float2 cs2[NP];                   // {c, s}
  __shared__ float fv[NPAD];

  int t = threadIdx.x;
  float* M = mats + (size_t)blockIdx.x*(NDATA*NDATA);

  // ---- load + symmetrize (flat over padded buffer, pads -> 0) + fro2 ----
  float fro2 = 0.f;
  for (int e = t; e < NFLAT; e += 64) {
    int i = e / LD, j = e % LD;
    float v = 0.f;
    if (i < NDATA && j < NDATA) v = 0.5f*(M[i*NDATA + j] + M[j*NDATA + i]);
    A[e] = v;
    U[e] = (i == j) ? 1.f : 0.f;
    fro2 += v*v;
  }
  #pragma unroll
  for (int o = 32; o > 0; o >>= 1) fro2 += __shfl_xor(fro2, o);
  float tol2 = __shfl(fro2, 0) * 1e-13f + 1e-30f;
  __syncthreads();

  // ---- hoisted per-thread item coords (round-invariant) ----
  int kC[NIT], kR[NIT], pqOff[NIT], csOff[NIT];
  #pragma unroll
  for (int m = 0; m < NIT; ++m) {
    int e = t + 64*m;
    if (e >= NITEM) e = 0;                     // dummy; guarded at use
    int i = e / NPAD, kx = e - i*NPAD;
    kC[m] = kx*4; kR[m] = kx*(LD*4); pqOff[m] = i*16; csOff[m] = i*8;
  }

  // ---- sweeps with early exit ----
  for (int sw = 0; sw < 10; ++sw) {
    if (sw >= 2) {
      float off2 = 0.f;
      for (int e = t; e < NFLAT; e += 64) {
        int i = e / LD, j = e % LD;
        float v = A[e];
        off2 += (i == j) ? 0.f : v*v;
      }
      #pragma unroll
      for (int o = 32; o > 0; o >>= 1) off2 += __shfl_xor(off2, o);
      off2 = __shfl(off2, 0);
      if (off2 < tol2) break;
    }
    for (int r = 0; r < NR; ++r) {
      if (t < NP) {
        int p, q;
        if (t == 0) { p = NPAD-1; q = r; }
        else {
          p = r + t; if (p >= NR) p -= NR;
          q = r - t; if (q < 0)   q += NR;
        }
        float app = A[p*LD + p], aqq = A[q*LD + q], apq = A[p*LD + q];
        float c = 1.f, s = 0.f;
        if (fabsf(apq) > 1e-36f) {
          float tau = (aqq - app) / (2.f*apq);
          float tt = 1.f / (fabsf(tau) + sqrtf(tau*tau + 1.f));
          tt = (tau >= 0.f) ? tt : -tt;
          c = rsqrtf(tt*tt + 1.f);
          s = tt * c;
        }
        pq4[t] = make_int4(p*4, q*4, p*(LD*4), q*(LD*4));
        cs2[t] = make_float2(c, s);
      }
      __syncthreads();
      #pragma unroll
      for (int m = 0; m < NIT; ++m) {                          // A <- A*J (cols p,q)
        if (m+1 < NIT || t < LASTV) {
          int4 P = PQ4(pqOff[m]);
          float2 C = CS2(csOff[m]);
          int ap = kR[m] + P.x, aq = kR[m] + P.y;
          float a0 = ALDS(ap), a1 = ALDS(aq);
          ALDS(ap) = C.x*a0 - C.y*a1;
          ALDS(aq) = C.y*a0 + C.x*a1;
        }
      }
      __syncthreads();
      #pragma unroll
      for (int m = 0; m < NIT; ++m) {                          // A <- J^T*A ; U <- U*J
        if (m+1 < NIT || t < LASTV) {
          int4 P = PQ4(pqOff[m]);
          float2 C = CS2(csOff[m]);
          int rp = P.z + kC[m], rq = P.w + kC[m];
          float a0 = ALDS(rp), a1 = ALDS(rq);
          ALDS(rp) = C.x*a0 - C.y*a1;
          ALDS(rq) = C.y*a0 + C.x*a1;
          int up = kR[m] + P.x, uq = kR[m] + P.y;
          float u0 = ULDS(up), u1 = ULDS(uq);
          ULDS(up) = C.x*u0 - C.y*u1;
          ULDS(uq) = C.y*u0 + C.x*u1;
        }
      }
      __syncthreads();
    }
  }

  // ---- f(w) ----
  if (t < NPAD) {
    float wv = A[t*LD + t];
    float f;
    if (MODE == 0)      f = logf(fmaxf(wv, 1e-9f));
    else if (MODE == 1) f = fmaxf(expf(wv), 1e-4f);
    else                f = fmaxf(wv, -9.210340371976182f);
    fv[t] = (t < NDATA) ? f : 0.f;
  }
  __syncthreads();
  // ---- A <- U * diag(fv) ----
  for (int e = t; e < NFLAT; e += 64) {
    int j = e % LD;
    float fj = (j < NPAD) ? fv[j] : 0.f;
    A[e] = U[e] * fj;
  }
  __syncthreads();
  // ---- M = (U f U^T), triangle only, mirrored write ----
  float nacc = 0.f;
  for (int e = t; e < NT; e += 64) {
    int i = 0, rem = e;
    while (rem >= NDATA - i) { rem -= NDATA - i; ++i; }
    int j = i + rem;
    int bi = i*(LD*4), bj = j*(LD*4);
    float acc = 0.f;
    #pragma unroll
    for (int k = 0; k < NPAD; ++k)
      acc += ALDS(bi + 4*k) * ULDS(bj + 4*k);
    M[i*NDATA + j] = acc;
    M[j*NDATA + i] = acc;
    nacc += (i == j) ? acc*acc : 2.f*acc*acc;
  }
  if (norms != nullptr) {
    #pragma unroll
    for (int o = 32; o > 0; o >>= 1) nacc += __shfl_down(nacc, o);
    if (t == 0) norms[blockIdx.x] = nacc;
  }
}

// ---------------- per-thread 4x4 eigh -> log, plus Frobenius^2 norm ----------------
template<int P, int Q>
__device__ __forceinline__ void rot4(float a[4][4], float u[4][4])
{
  float apq = a[P][Q];
  if (fabsf(apq) < 1e-36f) return;
  float app = a[P][P], aqq = a[Q][Q];
  float tau = (aqq - app) / (2.f*apq);
  float tt = 1.f / (fabsf(tau) + sqrtf(tau*tau + 1.f));
  if (tau < 0.f) tt = -tt;
  float c = 1.f / sqrtf(tt*tt + 1.f), s = tt*c;
  #pragma unroll
  for (int k = 0; k < 4; ++k) { float akp = a[k][P], akq = a[k][Q]; a[k][P] = c*akp - s*akq; a[k][Q] = s*akp + c*akq; }
  #pragma unroll
  for (int k = 0; k < 4; ++k) { float apk = a[P][k], aqk = a[Q][k]; a[P][k] = c*apk - s*aqk; a[Q][k] = s*apk + c*aqk; }
  #pragma unroll
  for (int k = 0; k < 4; ++k) { float ukp = u[k][P], ukq = u[k][Q]; u[k][P] = c*ukp - s*ukq; u[k][Q] = s*ukp + c*ukq; }
}

__global__ __launch_bounds__(256) void eigh4_kernel(float* __restrict__ kmats, float* __restrict__ qmats,
                                                    float* __restrict__ norms)
{
  int idx = blockIdx.x*256 + threadIdx.x;
  if (idx >= 23808) return;
  float* M = (idx < 23040) ? (kmats + (size_t)idx*16) : (qmats + (size_t)(idx - 23040)*16);
  float a[4][4], u[4][4];
  #pragma unroll
  for (int i = 0; i < 4; ++i)
    #pragma unroll
    for (int j = 0; j < 4; ++j) { a[i][j] = 0.5f*(M[i*4+j] + M[j*4+i]); u[i][j] = (i == j) ? 1.f : 0.f; }
  #pragma unroll 1
  for (int sw = 0; sw < 8; ++sw) {
    rot4<0,1>(a,u); rot4<0,2>(a,u); rot4<0,3>(a,u);
    rot4<1,2>(a,u); rot4<1,3>(a,u); rot4<2,3>(a,u);
  }
  float f[4];
  #pragma unroll
  for (int i = 0; i < 4; ++i) f[i] = logf(fmaxf(a[i][i], 1e-9f));
  float nrm = 0.f;
  #pragma unroll
  for (int i = 0; i < 4; ++i)
    #pragma unroll
    for (int j = 0; j < 4; ++j) {
      float acc = 0.f;
      #pragma unroll
      for (int k = 0; k < 4; ++k) acc += u[i][k]*f[k]*u[j][k];
      M[i*4+j] = acc; nrm += acc*acc;
    }
  norms[idx] = nrm;
}

// ---------------- attention 1: only output row j=29 needed ----------------
__global__ __launch_bounds__(64) void att1_kernel(
    const float* __restrict__ logK, const float* __restrict__ logQ,
    const float* __restrict__ kn, const float* __restrict__ qn,
    const float* __restrict__ logV, float* __restrict__ outlog1)
{
  __shared__ float lq[16];
  __shared__ float sscore[30];
  __shared__ float sp[30];
  int bt = blockIdx.x, t = threadIdx.x;
  if (t < 16) lq[t] = logQ[(size_t)bt*16 + t];
  __syncthreads();
  if (t < 30) {
    const float* lk = logK + ((size_t)bt*30 + t)*16;
    float cr = 0.f;
    #pragma unroll
    for (int e = 0; e < 16; ++e) cr += lk[e]*lq[e];
    float E = fmaxf(kn[bt*30 + t] + qn[bt] - 2.f*cr, 0.f);
    sscore[t] = 1.f/(1.f + log1pf(E));
  }
  __syncthreads();
  float mx = -1e30f;
  for (int i = 0; i < 30; ++i) mx = fmaxf(mx, sscore[i]);
  float sm = 0.f;
  for (int i = 0; i < 30; ++i) sm += expf(sscore[i] - mx);
  if (t < 30) sp[t] = expf(sscore[t] - mx)/sm;
  __syncthreads();
  const float* lv = logV + (size_t)bt*30*625;
  float* outp = outlog1 + (size_t)bt*625;
  for (int e = t; e < 625; e += 64) {
    float acc = 0.f;
    for (int i = 0; i < 30; ++i) acc += sp[i]*lv[(size_t)i*625 + e];
    outp[e] = acc;                      // symmetrization folded into next eigh's load
  }
}

// ---------------- stage D: Q2/K2/V2 = W^T xm W (18x18) ----------------
__global__ __launch_bounds__(64) void qkv2_kernel(
    const float* __restrict__ xm, const float* __restrict__ mq, const float* __restrict__ mk,
    const float* __restrict__ mv, float* __restrict__ q2, float* __restrict__ k2, float* __restrict__ v2)
{
  __shared__ float sx[625], sw[450], stmp[450];
  int bt = blockIdx.x, t = threadIdx.x;
  for (int e = t; e < 625; e += 64) sx[e] = xm[(size_t)bt*625 + e];
  for (int wi = 0; wi < 3; ++wi) {
    const float* W = (wi == 0) ? mq : (wi == 1) ? mk : mv;
    float* O = ((wi == 0) ? q2 : (wi == 1) ? k2 : v2) + (size_t)bt*324;
    for (int e = t; e < 450; e += 64) sw[e] = W[e];
    __syncthreads();
    for (int e = t; e < 450; e += 64) {
      int i = e / 18, b = e % 18;
      float acc = 0.f;
      for (int j = 0; j < 25; ++j) acc += sx[i*25 + j]*sw[j*18 + b];
      stmp[e] = acc;
    }
    __syncthreads();
    for (int e = t; e < 324; e += 64) {
      int a = e / 18, b = e % 18;
      float acc = 0.f;
      for (int i = 0; i < 25; ++i) acc += sw[i*18 + a]*stmp[i*18 + b];
      O[e] = acc;
    }
    __syncthreads();
  }
}

// ---------------- attention 2 (m=3, all outputs) ----------------
__global__ __launch_bounds__(64) void att2_kernel(
    const float* __restrict__ logQ2, const float* __restrict__ logK2, const float* __restrict__ logV2,
    const float* __restrict__ norms, float* __restrict__ outlog2)
{
  __shared__ float S[3][3];   // score[i][j]
  __shared__ float PT[3][3];  // P[j][i]
  int b = blockIdx.x, t = threadIdx.x;
  if (t < 9) {
    int i = t / 3, j = t % 3;
    const float* lk = logK2 + ((size_t)b*3 + i)*324;
    const float* lq = logQ2 + ((size_t)b*3 + j)*324;
    float cr = 0.f;
    for (int e = 0; e < 324; ++e) cr += lk[e]*lq[e];
    float E = fmaxf(norms[768 + b*3 + i] + norms[b*3 + j] - 2.f*cr, 0.f);
    S[i][j] = 1.f/(1.f + log1pf(E));
  }
  __syncthreads();
  if (t < 3) {
    float m = fmaxf(S[0][t], fmaxf(S[1][t], S[2][t]));
    float e0 = expf(S[0][t]-m), e1 = expf(S[1][t]-m), e2 = expf(S[2][t]-m);
    float ssum = e0 + e1 + e2;
    PT[t][0] = e0/ssum; PT[t][1] = e1/ssum; PT[t][2] = e2/ssum;
  }
  __syncthreads();
  for (int e = t; e < 324; e += 64) {
    float l0 = logV2[((size_t)b*3 + 0)*324 + e];
    float l1 = logV2[((size_t)b*3 + 1)*324 + e];
    float l2 = logV2[((size_t)b*3 + 2)*324 + e];
    #pragma unroll
    for (int j = 0; j < 3; ++j)
      outlog2[((size_t)b*3 + j)*324 + e] = PT[j][0]*l0 + PT[j][1]*l1 + PT[j][2]*l2;
  }
}

// ---------------- features + final linear ----------------
__global__ __launch_bounds__(64) void feat_kernel(
    const float* __restrict__ Lg, const float* __restrict__ lw, const float* __restrict__ lb,
    float* __restrict__ outp)
{
  __shared__ int tri_i[171], tri_j[171];
  int b = blockIdx.x, t = threadIdx.x;
  if (t == 0) { int f = 0; for (int i = 0; i < 18; ++i) for (int j = i; j < 18; ++j) { tri_i[f] = i; tri_j[f] = j; ++f; } }
  __syncthreads();
  float a0 = 0.f, a1 = 0.f, a2 = 0.f, a3 = 0.f;
  const float SQ2 = 1.41421356237309515f;
  for (int f = t; f < 513; f += 64) {
    int tt = f / 171, r = f % 171;
    int i = tri_i[r], j = tri_j[r];
    float coef = (i == j) ? 1.f : SQ2;
    float v = Lg[((size_t)b*3 + tt)*324 + i*18 + j] * coef;
    a0 += v*lw[0*513 + f]; a1 += v*lw[1*513 + f]; a2 += v*lw[2*513 + f]; a3 += v*lw[3*513 + f];
  }
  #pragma unroll
  for (int off = 32; off > 0; off >>= 1) {
    a0 += __shfl_down(a0, off); a1 += __shfl_down(a1, off);
    a2 += __shfl_down(a2, off); a3 += __shfl_down(a3, off);
  }
  if (t == 0) {
    outp[b*4 + 0] = a0 + lb[0]; outp[b*4 + 1] = a1 + lb[1];
    outp[b*4 + 2] = a2 + lb[2]; outp[b*4 + 3] = a3 + lb[3];
  }
}

// ---------------------------------------------------------------------------
extern "C" void kernel_launch(void* const* d_in, const int* in_sizes, int n_in,
                              void* d_out, int out_size, void* d_ws, size_t ws_size,
                              hipStream_t stream)
{
  const float* x    = (const float*)d_in[0];
  const float* c1w  = (const float*)d_in[1];
  const float* c1b  = (const float*)d_in[2];
  const float* bn1g = (const float*)d_in[3];
  const float* bn1b = (const float*)d_in[4];
  const float* bn1m = (const float*)d_in[5];
  const float* bn1v = (const float*)d_in[6];
  const float* c2w  = (const float*)d_in[7];
  const float* c2b  = (const float*)d_in[8];
  const float* bn2g = (const float*)d_in[9];
  const float* bn2b = (const float*)d_in[10];
  const float* bn2m = (const float*)d_in[11];
  const float* bn2v = (const float*)d_in[12];
  const float* sk0  = (const float*)d_in[14];
  const float* sv0  = (const float*)d_in[15];
  const float* sk1  = (const float*)d_in[17];
  const float* sv1  = (const float*)d_in[18];
  const float* sk2  = (const float*)d_in[20];
  const float* sv2  = (const float*)d_in[21];
  const float* sq3  = (const float*)d_in[22];
  const float* sk3  = (const float*)d_in[23];
  const float* sv3  = (const float*)d_in[24];
  const float* mq   = (const float*)d_in[25];
  const float* mk   = (const float*)d_in[26];
  const float* mv   = (const float*)d_in[27];
  const float* lw   = (const float*)d_in[28];
  const float* lb   = (const float*)d_in[29];
  float* outp = (float*)d_out;

  float* ws = (float*)d_ws;
  // workspace layout (floats); Vbuf reuses dead ybn1+sig space
  float* covs = ws;                       // 768*625        = 480000
  float* ybn1 = ws + 480000;              // 256*22*1000    = 5632000
  float* sig  = ws + 6112000;             // 256*25*1001    = 6406400 -> ends 12518400
  float* Vbuf = ws + 480000;              // 23040*625      = 14400000 -> ends 14880000 (after covs; ybn1/sig dead)
  float* Kbuf = ws + 14880000;            // 23040*16       = 368640
  float* Qbuf = ws + 15248640;            // 768*16         = 12288
  float* knb  = ws + 15260928;            // 23808
  float* ol1  = ws + 15284736;            // 768*625        = 480000   (becomes xm in place)
  float* qkv2 = ws + 15764736;            // 3*768*324      = 746496
  float* nrm2 = ws + 16511232;            // 2304
  float* ol2  = ws + 16513536;            // 768*324        = 248832   (becomes Lg in place)
  // total 16762368 floats = ~64 MiB

  conv1_kernel<<<1000, 256, 0, stream>>>(x, c1w, c1b, bn1g, bn1b, bn1m, bn1v, ybn1);
  conv2_kernel<<<1001, 256, 0, stream>>>(ybn1, c2w, c2b, bn2g, bn2b, bn2m, bn2v, sig);
  spd_kernel<<<768, 256, 0, stream>>>(sig, covs);
  build_windows_kernel<<<23040, 64, 0, stream>>>(covs, sk0, sk1, sk2, sk3, sv0, sv1, sv2, sv3, sq3,
                                                 Vbuf, Kbuf, Qbuf);
  eigh_kernel<26,25,0><<<23040, 64, 0, stream>>>(Vbuf, nullptr);           // logV in place
  eigh4_kernel<<<93, 256, 0, stream>>>(Kbuf, Qbuf, knb);                   // logK/logQ + norms
  att1_kernel<<<768, 64, 0, stream>>>(Kbuf, Qbuf, knb, knb + 23040, Vbuf, ol1);
  eigh_kernel<26,25,1><<<768, 64, 0, stream>>>(ol1, nullptr);              // xm = rect(exp(.)) in place
  qkv2_kernel<<<768, 64, 0, stream>>>(ol1, mq, mk, mv, qkv2, qkv2 + 248832, qkv2 + 497664);
  eigh_kernel<18,18,0><<<2304, 64, 0, stream>>>(qkv2, nrm2);               // logQ2/logK2/logV2 + norms
  att2_kernel<<<256, 64, 0, stream>>>(qkv2, qkv2 + 248832, qkv2 + 497664, nrm2, ol2);
  eigh_kernel<18,18,2><<<768, 64, 0, stream>>>(ol2, nullptr);              // Lg = max(w, ln 1e-4) in place
  feat_kernel<<<256, 64, 0, stream>>>(ol2, lw, lb, outp);
}